// Round 6
// baseline (216.389 us; speedup 1.0000x reference)
//
#include <hip/hip_runtime.h>
#include <math.h>

#define NTOK 131072
#define KC   1024
#define DIMV 64
#define TPB  512                 // tokens per block (8 groups x 64)
#define CMAX 128                 // per-wave candidate capacity (expect ~37)
#define EPSH 1e-3f               // EPS/2 in halved-distance units (EPS=2e-3,
                                 // verified rounds 3-5)

#define OUT_LOSS 0
#define OUT_Q    1
#define OUT_PERP (1 + NTOK * DIMV)
#define OUT_IDX  (2 + NTOK * DIMV)

typedef __attribute__((ext_vector_type(8))) short short8;
typedef __attribute__((ext_vector_type(4))) float f32x4;

// numpy pairwise_sum mimic for n=64 of v[i]*v[i] (no FMA) — bit-identical
// to the verified kernel.
__device__ __forceinline__ float sumsq64_np(const float v[DIMV]) {
#pragma clang fp contract(off)
  {
    float r[8];
#pragma unroll
    for (int j = 0; j < 8; ++j) r[j] = v[j] * v[j];
#pragma unroll
    for (int i = 8; i < 64; i += 8) {
#pragma unroll
      for (int j = 0; j < 8; ++j) r[j] += v[i + j] * v[i + j];
    }
    return ((r[0] + r[1]) + (r[2] + r[3])) + ((r[4] + r[5]) + (r[6] + r[7]));
  }
}

__device__ __forceinline__ unsigned short bf16rne(float f) {
  unsigned int u = __float_as_uint(f);
  return (unsigned short)((u + 0x7fffu + ((u >> 16) & 1u)) >> 16);
}

// Fused kernel. 16 waves; waves pair up: group q = wv>>1 owns 64 tokens,
// the two waves of a group each scan HALF the codebook (32 tiles) ->
// half the LDS B-traffic of round 4 and 4x compute per tile for latency
// hiding, while keeping 4 waves/SIMD.
__global__ void __launch_bounds__(1024)
vq_fused(const float* __restrict__ xin, const float* __restrict__ cb,
         float* __restrict__ out, float* __restrict__ ws) {
  __shared__ __align__(16) char s_pack[131072];   // 128 KB bf16-hi fragments
  __shared__ float s_norm[KC];
  __shared__ unsigned int s_hist[KC];
  __shared__ float s_pmin[16][64];                // per-wave token mins
  __shared__ float s_gmin[8][64];                 // per-group combined mins
  __shared__ unsigned int s_cand[16][CMAX];
  __shared__ unsigned long long s_key[8][64];
  __shared__ int s_cnt[16];
  __shared__ int s_last;

  const int tid = threadIdx.x;
  const int l   = tid & 63;
  const int wv  = tid >> 6;
  const int cls = l & 15;      // code-within-tile / D-col; also A-token row
  const int g   = l >> 4;      // k-subgroup / D-row group
  const int q   = wv >> 1;     // token group (0..7), 64 tokens each
  const int wl  = wv & 1;      // codebook half (0..1), 32 tiles each
  const int blk = blockIdx.x;
  const int tb  = blk * TPB + q * 64;

  float* ws_mse = ws;
  unsigned int* ws_hist = (unsigned int*)ws + 1;
  unsigned int* ws_done = (unsigned int*)ws + 1 + KC;

  // ---- in-block pack: bf16-hi B-fragments (bit-identical bytes to the
  //      verified pack: tile t, cell f, lane cl) ----
  for (int c = tid; c < 8192; c += 1024) {
    const int tile = c >> 7, f = (c >> 6) & 1, cl = c & 63;
    const int code = tile * 16 + (cl & 15);
    const int kb = f * 32 + (cl >> 4) * 8;
    const float4* src = (const float4*)(cb + code * DIMV + kb);
    float4 v0 = src[0], v1 = src[1];
    float v[8] = {v0.x, v0.y, v0.z, v0.w, v1.x, v1.y, v1.z, v1.w};
    unsigned int hw[4];
#pragma unroll
    for (int j = 0; j < 4; ++j) {
      hw[j] = (unsigned int)bf16rne(v[2 * j]) |
              ((unsigned int)bf16rne(v[2 * j + 1]) << 16);
    }
    *(uint4*)(s_pack + tile * 2048 + f * 1024 + cl * 16) =
        make_uint4(hw[0], hw[1], hw[2], hw[3]);
  }
  // ---- exact code norms (verified chain), one per thread; hist init ----
  {
    const int k = tid;
    float row[DIMV];
    const float4* r4 = (const float4*)(cb + (size_t)k * DIMV);
#pragma unroll
    for (int i = 0; i < 16; ++i) {
      float4 t = r4[i];
      row[4 * i + 0] = t.x; row[4 * i + 1] = t.y;
      row[4 * i + 2] = t.z; row[4 * i + 3] = t.w;
    }
    s_norm[k] = sumsq64_np(row);
    s_hist[k] = 0u;
  }
  if (tid < 512) s_key[tid >> 6][tid & 63] = ~0ull;
  if (tid < 16) s_cnt[tid] = 0;

  // ---- A-fragments (bf16-hi) for 4 token sub-groups of this group ----
  short8 af[4][2];
#pragma unroll
  for (int grp = 0; grp < 4; ++grp) {
    const float* xr = xin + (size_t)(tb + grp * 16 + cls) * DIMV + g * 8;
#pragma unroll
    for (int kc = 0; kc < 2; ++kc) {
      float4 v0 = *(const float4*)(xr + kc * 32);
      float4 v1 = *(const float4*)(xr + kc * 32 + 4);
      float vv[8] = {v0.x, v0.y, v0.z, v0.w, v1.x, v1.y, v1.z, v1.w};
#pragma unroll
      for (int j = 0; j < 8; ++j) af[grp][kc][j] = (short)bf16rne(vv[j]);
    }
  }
  __syncthreads();   // B1: pack + norms visible

  // ---------------- pass 1: per-token min of s~/2 = norm/2 - dot~ ---------
  const int tbase = wl * 32;
  float minv[4][4];
#pragma unroll
  for (int grp = 0; grp < 4; ++grp)
#pragma unroll
    for (int j = 0; j < 4; ++j) minv[grp][j] = INFINITY;

  short8 b0 = *(const short8*)(s_pack + tbase * 2048 + l * 16);
  short8 b1 = *(const short8*)(s_pack + tbase * 2048 + 1024 + l * 16);
  float nr = s_norm[tbase * 16 + cls];
#pragma unroll 2
  for (int t = 0; t < 32; ++t) {
    short8 c0 = b0, c1 = b1;
    float cc = -0.5f * nr;
    if (t < 31) {
      const char* bp = s_pack + (tbase + t + 1) * 2048 + l * 16;
      b0 = *(const short8*)(bp);
      b1 = *(const short8*)(bp + 1024);
      nr = s_norm[(tbase + t + 1) * 16 + cls];
    }
#pragma unroll
    for (int grp = 0; grp < 4; ++grp) {
      f32x4 acc = {cc, cc, cc, cc};
      acc = __builtin_amdgcn_mfma_f32_16x16x32_bf16(af[grp][0], c0, acc, 0, 0, 0);
      acc = __builtin_amdgcn_mfma_f32_16x16x32_bf16(af[grp][1], c1, acc, 0, 0, 0);
#pragma unroll
      for (int j = 0; j < 4; ++j)
        minv[grp][j] = fminf(minv[grp][j], -acc[j]);
    }
  }
  // reduce across the 16 code-columns (lanes sharing g)
#pragma unroll
  for (int mask = 1; mask < 16; mask <<= 1) {
#pragma unroll
    for (int grp = 0; grp < 4; ++grp)
#pragma unroll
      for (int j = 0; j < 4; ++j)
        minv[grp][j] = fminf(minv[grp][j], __shfl_xor(minv[grp][j], mask, 64));
  }
  // publish per-wave token mins (token m = grp*16 + g*4 + j)
  if (cls == 0) {
#pragma unroll
    for (int grp = 0; grp < 4; ++grp) {
      float4 v = make_float4(minv[grp][0], minv[grp][1], minv[grp][2], minv[grp][3]);
      *(float4*)&s_pmin[wv][grp * 16 + g * 4] = v;
    }
  }
  __syncthreads();   // B2
  if (tid < 512) {
    const int q2 = tid >> 6, m = tid & 63;
    s_gmin[q2][m] = fminf(s_pmin[q2 * 2][m], s_pmin[q2 * 2 + 1][m]);
  }
  __syncthreads();   // B3
  // thresholds (reuse minv): group-combined min + EPSH
#pragma unroll
  for (int grp = 0; grp < 4; ++grp) {
    float4 t4 = *(const float4*)&s_gmin[q][grp * 16 + g * 4];
    minv[grp][0] = t4.x + EPSH; minv[grp][1] = t4.y + EPSH;
    minv[grp][2] = t4.z + EPSH; minv[grp][3] = t4.w + EPSH;
  }

  // ---------------- pass 2: collect candidates s~/2 <= min + EPSH ---------
  b0 = *(const short8*)(s_pack + tbase * 2048 + l * 16);
  b1 = *(const short8*)(s_pack + tbase * 2048 + 1024 + l * 16);
  nr = s_norm[tbase * 16 + cls];
#pragma unroll 2
  for (int t = 0; t < 32; ++t) {
    short8 c0 = b0, c1 = b1;
    float cc = -0.5f * nr;
    if (t < 31) {
      const char* bp = s_pack + (tbase + t + 1) * 2048 + l * 16;
      b0 = *(const short8*)(bp);
      b1 = *(const short8*)(bp + 1024);
      nr = s_norm[(tbase + t + 1) * 16 + cls];
    }
#pragma unroll
    for (int grp = 0; grp < 4; ++grp) {
      f32x4 acc = {cc, cc, cc, cc};
      acc = __builtin_amdgcn_mfma_f32_16x16x32_bf16(af[grp][0], c0, acc, 0, 0, 0);
      acc = __builtin_amdgcn_mfma_f32_16x16x32_bf16(af[grp][1], c1, acc, 0, 0, 0);
#pragma unroll
      for (int j = 0; j < 4; ++j) {
        if (-acc[j] <= minv[grp][j]) {
          int pos = atomicAdd(&s_cnt[wv], 1);
          if (pos < CMAX)
            s_cand[wv][pos] =
                ((unsigned int)(grp * 16 + g * 4 + j) << 10) |
                (unsigned int)((tbase + t) * 16 + cls);
        }
      }
    }
  }
  asm volatile("s_waitcnt lgkmcnt(0)" ::: "memory");
  const int cnt = s_cnt[wv];
  int n = cnt < CMAX ? cnt : CMAX;

  // ---------------- exact re-score (bit-identical chains) -----------------
  for (int base = 0; base < n; base += 64) {
    int i = base + l;
    if (i < n) {
      unsigned int pk = s_cand[wv][i];
      int m = (int)(pk >> 10), k = (int)(pk & 1023);
      const float4* xr4 = (const float4*)(xin + (size_t)(tb + m) * DIMV);
      const float4* er4 = (const float4*)(cb + (size_t)k * DIMV);
      float r[8];
      float dot = 0.0f;
#pragma unroll
      for (int s = 0; s < 8; ++s) {
        float4 a = xr4[2 * s], b = xr4[2 * s + 1];
        float4 ea = er4[2 * s], eb = er4[2 * s + 1];
        float xv[8] = {a.x, a.y, a.z, a.w, b.x, b.y, b.z, b.w};
        float ev[8] = {ea.x, ea.y, ea.z, ea.w, eb.x, eb.y, eb.z, eb.w};
        {
#pragma clang fp contract(off)
#pragma unroll
          for (int j = 0; j < 8; ++j) {
            float sq = xv[j] * xv[j];
            r[j] = (s == 0) ? sq : (r[j] + sq);
          }
        }
#pragma unroll
        for (int j = 0; j < 8; ++j) dot = __builtin_fmaf(ev[j], xv[j], dot);
      }
      float xx = ((r[0] + r[1]) + (r[2] + r[3])) + ((r[4] + r[5]) + (r[6] + r[7]));
      float d = (xx - 2.0f * dot) + s_norm[k];
      unsigned long long key =
          ((unsigned long long)__float_as_uint(d) << 10) | (unsigned long long)k;
      atomicMin(&s_key[q][m], key);
    }
  }

  // safety net (never expected): overflow -> exact scan of this wave's half
  if (cnt > CMAX) {
    const int m = l;   // 64 tokens, one per lane
    float xv[DIMV];
    const float4* xr4 = (const float4*)(xin + (size_t)(tb + m) * DIMV);
#pragma unroll
    for (int i = 0; i < 16; ++i) {
      float4 t4 = xr4[i];
      xv[4 * i + 0] = t4.x; xv[4 * i + 1] = t4.y;
      xv[4 * i + 2] = t4.z; xv[4 * i + 3] = t4.w;
    }
    float xx = sumsq64_np(xv);
    float bd = INFINITY; int bk = 0;
    for (int k = wl * 512; k < wl * 512 + 512; ++k) {
      const float* e = cb + (size_t)k * DIMV;
      float dot = 0.0f;
#pragma unroll
      for (int i = 0; i < DIMV; ++i) dot = __builtin_fmaf(e[i], xv[i], dot);
      float d = (xx - 2.0f * dot) + s_norm[k];
      if (d < bd) { bd = d; bk = k; }
    }
    unsigned long long key =
        ((unsigned long long)__float_as_uint(bd) << 10) | (unsigned long long)bk;
    atomicMin(&s_key[q][m], key);
  }
  __syncthreads();   // B4: all key merges complete

  // ---------------- epilogue: 2 threads per token (verified pattern) ------
  {
    const int tok = tid >> 1, h = tid & 1;
    const int token = blk * TPB + tok;
    unsigned long long key = s_key[tok >> 6][tok & 63];
    const int bk = (int)(key & 1023ull);
    if (h == 0) {
      out[OUT_IDX + token] = (float)bk;
      atomicAdd(&s_hist[bk], 1u);
    }
    const float4* q4 = (const float4*)(cb + (size_t)bk * DIMV + h * 32);
    const float4* x4 = (const float4*)(xin + (size_t)token * DIMV + h * 32);
    float* oq = out + OUT_Q + (size_t)token * DIMV + h * 32;
    float mse_part = 0.0f;
#pragma unroll
    for (int rr = 0; rr < 8; ++rr) {
      float4 qv = q4[rr], xv = x4[rr];
      float d0 = qv.x - xv.x, d1 = qv.y - xv.y;
      float d2 = qv.z - xv.z, d3 = qv.w - xv.w;
      float4 o;
      o.x = xv.x + d0; o.y = xv.y + d1; o.z = xv.z + d2; o.w = xv.w + d3;
      mse_part = __builtin_fmaf(d0, d0, mse_part);
      mse_part = __builtin_fmaf(d1, d1, mse_part);
      mse_part = __builtin_fmaf(d2, d2, mse_part);
      mse_part = __builtin_fmaf(d3, d3, mse_part);
      *(float4*)(oq + 4 * rr) = o;
    }
#pragma unroll
    for (int mask = 1; mask < 64; mask <<= 1)
      mse_part += __shfl_xor(mse_part, mask, 64);
    if (l == 0) atomicAdd(ws_mse, mse_part);
  }
  __syncthreads();   // B5: all s_hist atomics done
  {
    unsigned int c = s_hist[tid];
    if (c) atomicAdd(&ws_hist[tid], c);
  }

  // ---------------- last-block final: perplexity + loss -------------------
  if (tid == 0) {
    __threadfence();
    unsigned int tkt = atomicAdd(ws_done, 1u);
    s_last = (tkt == (unsigned int)(gridDim.x - 1)) ? 1 : 0;
  }
  __syncthreads();
  if (s_last) {
    __threadfence();
    unsigned int c = atomicAdd(&ws_hist[tid], 0u);   // coherent read
    float p = (float)c / 131072.0f;                  // exact (2^17)
    s_norm[tid] = p * logf(p + 1e-10f);              // p==0 -> 0
    __syncthreads();
#pragma unroll
    for (int s = 512; s > 0; s >>= 1) {
      if (tid < s) s_norm[tid] += s_norm[tid + s];
      __syncthreads();
    }
    if (tid == 0) {
      out[OUT_PERP] = expf(-s_norm[0]);
      float mse = atomicAdd(ws_mse, 0.0f) / 8388608.0f;   // exact (2^23)
      out[OUT_LOSS] = mse + 0.25f * mse;
    }
  }
}

extern "C" void kernel_launch(void* const* d_in, const int* in_sizes, int n_in,
                              void* d_out, int out_size, void* d_ws, size_t ws_size,
                              hipStream_t stream) {
  (void)in_sizes; (void)n_in; (void)out_size; (void)ws_size;
  const float* xin = (const float*)d_in[0];
  const float* cb  = (const float*)d_in[1];
  float* out = (float*)d_out;
  float* ws  = (float*)d_ws;   // [0]=mse, [1..1024]=hist, [1025]=done ticket

  hipMemsetAsync(d_ws, 0, sizeof(float) * (1 + KC + 1), stream);
  hipLaunchKernelGGL(vq_fused, dim3(NTOK / TPB), dim3(1024), 0, stream,
                     xin, cb, out, ws);
}

// Round 7
// 181.233 us; speedup vs baseline: 1.1940x; 1.1940x over previous
//
#include <hip/hip_runtime.h>
#include <math.h>

#define NTOK 131072
#define KC   1024
#define DIMV 64
#define NWAVE 16
#define TPW  32                  // tokens per wave (2 groups of 16)
#define TPB  (NWAVE * TPW)       // 512 tokens per block
#define CMAX 128                 // per-wave candidate capacity (expect ~37)
#define EPSH 1e-3f               // EPS/2 in halved-distance units (EPS=2e-3,
                                 // bound verified rounds 3-6, absmax 0.0)

#define OUT_LOSS 0
#define OUT_Q    1
#define OUT_PERP (1 + NTOK * DIMV)
#define OUT_IDX  (2 + NTOK * DIMV)

// workspace floats: [0]=mse, [1..1024]=hist, [1025]=done ticket,
// [1026..2049]=norms; packed bf16-hi fragments at byte 12288 (128 KB)
#define WS_HIST 1
#define WS_TKT  1025
#define WS_NORM 1026
#define WS_PACK_BYTES 12288

typedef __attribute__((ext_vector_type(8))) short short8;
typedef __attribute__((ext_vector_type(4))) float f32x4;

// numpy pairwise_sum mimic for n=64 of v[i]*v[i] (no FMA) — bit-identical
// to the verified kernel.
__device__ __forceinline__ float sumsq64_np(const float v[DIMV]) {
#pragma clang fp contract(off)
  {
    float r[8];
#pragma unroll
    for (int j = 0; j < 8; ++j) r[j] = v[j] * v[j];
#pragma unroll
    for (int i = 8; i < 64; i += 8) {
#pragma unroll
      for (int j = 0; j < 8; ++j) r[j] += v[i + j] * v[i + j];
    }
    return ((r[0] + r[1]) + (r[2] + r[3])) + ((r[4] + r[5]) + (r[6] + r[7]));
  }
}

__device__ __forceinline__ unsigned short bf16rne(float f) {
  unsigned int u = __float_as_uint(f);
  return (unsigned short)((u + 0x7fffu + ((u >> 16) & 1u)) >> 16);
}

// ---------------- pack: bf16-hi B-fragments + exact norms + ws zeroing -----
// (verified round 3/4 pack, plus zeroing mse/hist/ticket so no memset
// dispatch is needed; zero region [0..1025] is disjoint from norms.)
__global__ void __launch_bounds__(256)
vq_pack_kernel(const float* __restrict__ cb, float* __restrict__ ws) {
  const int e = blockIdx.x * 256 + threadIdx.x;   // 0..8191
  if (e < 1026) ws[e] = 0.0f;
  const int tile = e >> 7, f = (e >> 6) & 1, l = e & 63;
  const int code = tile * 16 + (l & 15);
  const int kb = f * 32 + (l >> 4) * 8;
  const float4* src = reinterpret_cast<const float4*>(cb + code * DIMV + kb);
  float4 v0 = src[0], v1 = src[1];
  float v[8] = {v0.x, v0.y, v0.z, v0.w, v1.x, v1.y, v1.z, v1.w};
  unsigned int hw[4];
#pragma unroll
  for (int j = 0; j < 4; ++j) {
    hw[j] = (unsigned int)bf16rne(v[2 * j]) |
            ((unsigned int)bf16rne(v[2 * j + 1]) << 16);
  }
  char* pack = (char*)ws + WS_PACK_BYTES;
  *(uint4*)(pack + tile * 2048 + f * 1024 + l * 16) =
      make_uint4(hw[0], hw[1], hw[2], hw[3]);
  if (e < KC) {
    float row[DIMV];
    const float4* r4 = reinterpret_cast<const float4*>(cb + e * DIMV);
#pragma unroll
    for (int i = 0; i < 16; ++i) {
      float4 t = r4[i];
      row[4 * i + 0] = t.x; row[4 * i + 1] = t.y;
      row[4 * i + 2] = t.z; row[4 * i + 3] = t.w;
    }
    ws[WS_NORM + e] = sumsq64_np(row);
  }
}

// ---------------- main: round-4 structure + prefetch + fused final ---------
__global__ void __launch_bounds__(1024)
vq_main_mfma(const float* __restrict__ xin, const float* __restrict__ cb,
             float* __restrict__ out, float* __restrict__ ws) {
  __shared__ __align__(16) char s_pack[131072];       // 128 KB packed codebook
  __shared__ float s_norm[KC];
  __shared__ unsigned int s_hist[KC];
  __shared__ unsigned int s_cand[NWAVE][CMAX];
  __shared__ unsigned long long s_key[NWAVE][TPW];
  __shared__ int s_cnt[NWAVE];
  __shared__ int s_last;

  const int tid = threadIdx.x;
  const int l   = tid & 63;
  const int wv  = tid >> 6;
  const int cls = l & 15;     // code-within-tile / D-col; A-token row
  const int g   = l >> 4;     // k-subgroup / D-row group
  const int blk = blockIdx.x;
  const int tb  = blk * TPB + wv * TPW;

  float* ws_mse = ws;
  unsigned int* ws_hist = (unsigned int*)ws + WS_HIST;
  unsigned int* ws_done = (unsigned int*)ws + WS_TKT;
  const float* ws_norm = ws + WS_NORM;
  const char* pack = (const char*)ws + WS_PACK_BYTES;

  // ---- prologue: stage pack (128 KB) + norms; init hist/keys/cnt ----
  {
    const uint4* src = (const uint4*)pack;
    uint4* dst = (uint4*)s_pack;
#pragma unroll
    for (int i = 0; i < 8; ++i) dst[tid + i * 1024] = src[tid + i * 1024];
  }
  s_norm[tid] = ws_norm[tid];
  s_hist[tid] = 0u;
  if (tid < NWAVE * TPW) s_key[tid >> 5][tid & 31] = ~0ull;
  if (tid < NWAVE) s_cnt[tid] = 0;
  __syncthreads();

  // A-fragments (bf16-hi) for 2 token groups: row = cls, k = kc*32 + g*8 + j
  short8 af[2][2];
#pragma unroll
  for (int grp = 0; grp < 2; ++grp) {
    const float* xr = xin + (size_t)(tb + grp * 16 + cls) * DIMV + g * 8;
#pragma unroll
    for (int kc = 0; kc < 2; ++kc) {
      float4 v0 = *(const float4*)(xr + kc * 32);
      float4 v1 = *(const float4*)(xr + kc * 32 + 4);
      float vv[8] = {v0.x, v0.y, v0.z, v0.w, v1.x, v1.y, v1.z, v1.w};
#pragma unroll
      for (int j = 0; j < 8; ++j) af[grp][kc][j] = (short)bf16rne(vv[j]);
    }
  }

  // ---------------- pass 1: per-token min of s~/2 = norm/2 - dot~ ---------
  // C-operand carries -norm/2 so s~/2 = -acc; min-update is one v_min with
  // neg modifier (verified r5/r6). Depth-1 prefetch of next tile's B/norm.
  float minv[2][4];
#pragma unroll
  for (int grp = 0; grp < 2; ++grp)
#pragma unroll
    for (int j = 0; j < 4; ++j) minv[grp][j] = INFINITY;

  short8 b0 = *(const short8*)(s_pack + l * 16);
  short8 b1 = *(const short8*)(s_pack + 1024 + l * 16);
  float nr = s_norm[cls];
#pragma unroll 2
  for (int t = 0; t < 64; ++t) {
    short8 c0 = b0, c1 = b1;
    float cc = -0.5f * nr;
    if (t < 63) {
      const char* bp = s_pack + (t + 1) * 2048 + l * 16;
      b0 = *(const short8*)(bp);
      b1 = *(const short8*)(bp + 1024);
      nr = s_norm[(t + 1) * 16 + cls];
    }
#pragma unroll
    for (int grp = 0; grp < 2; ++grp) {
      f32x4 acc = {cc, cc, cc, cc};
      acc = __builtin_amdgcn_mfma_f32_16x16x32_bf16(af[grp][0], c0, acc, 0, 0, 0);
      acc = __builtin_amdgcn_mfma_f32_16x16x32_bf16(af[grp][1], c1, acc, 0, 0, 0);
#pragma unroll
      for (int j = 0; j < 4; ++j)
        minv[grp][j] = fminf(minv[grp][j], -acc[j]);
    }
  }
  // reduce across the 16 code-columns (lanes sharing g)
#pragma unroll
  for (int mask = 1; mask < 16; mask <<= 1) {
#pragma unroll
    for (int grp = 0; grp < 2; ++grp)
#pragma unroll
      for (int j = 0; j < 4; ++j)
        minv[grp][j] = fminf(minv[grp][j], __shfl_xor(minv[grp][j], mask, 64));
  }
  float thr[2][4];
#pragma unroll
  for (int grp = 0; grp < 2; ++grp)
#pragma unroll
    for (int j = 0; j < 4; ++j) thr[grp][j] = minv[grp][j] + EPSH;

  // ---------------- pass 2: collect candidates s~/2 <= min + EPSH ---------
  b0 = *(const short8*)(s_pack + l * 16);
  b1 = *(const short8*)(s_pack + 1024 + l * 16);
  nr = s_norm[cls];
#pragma unroll 2
  for (int t = 0; t < 64; ++t) {
    short8 c0 = b0, c1 = b1;
    float cc = -0.5f * nr;
    if (t < 63) {
      const char* bp = s_pack + (t + 1) * 2048 + l * 16;
      b0 = *(const short8*)(bp);
      b1 = *(const short8*)(bp + 1024);
      nr = s_norm[(t + 1) * 16 + cls];
    }
#pragma unroll
    for (int grp = 0; grp < 2; ++grp) {
      f32x4 acc = {cc, cc, cc, cc};
      acc = __builtin_amdgcn_mfma_f32_16x16x32_bf16(af[grp][0], c0, acc, 0, 0, 0);
      acc = __builtin_amdgcn_mfma_f32_16x16x32_bf16(af[grp][1], c1, acc, 0, 0, 0);
#pragma unroll
      for (int j = 0; j < 4; ++j) {
        if (-acc[j] <= thr[grp][j]) {
          int pos = atomicAdd(&s_cnt[wv], 1);
          if (pos < CMAX)
            s_cand[wv][pos] =
                ((unsigned int)(grp * 16 + g * 4 + j) << 10) |
                (unsigned int)(t * 16 + cls);
        }
      }
    }
  }
  asm volatile("s_waitcnt lgkmcnt(0)" ::: "memory");
  const int cnt = s_cnt[wv];
  int n = cnt < CMAX ? cnt : CMAX;

  // ---------------- exact re-score (bit-identical chains) -----------------
  for (int base = 0; base < n; base += 64) {
    int i = base + l;
    if (i < n) {
      unsigned int pk = s_cand[wv][i];
      int m = (int)(pk >> 10), k = (int)(pk & 1023);
      const float4* xr4 = (const float4*)(xin + (size_t)(tb + m) * DIMV);
      const float4* er4 = (const float4*)(cb + (size_t)k * DIMV);
      float r[8];
      float dot = 0.0f;
#pragma unroll
      for (int s = 0; s < 8; ++s) {
        float4 a = xr4[2 * s], b = xr4[2 * s + 1];
        float4 ea = er4[2 * s], eb = er4[2 * s + 1];
        float xv[8] = {a.x, a.y, a.z, a.w, b.x, b.y, b.z, b.w};
        float ev[8] = {ea.x, ea.y, ea.z, ea.w, eb.x, eb.y, eb.z, eb.w};
        {
#pragma clang fp contract(off)
#pragma unroll
          for (int j = 0; j < 8; ++j) {
            float sq = xv[j] * xv[j];
            r[j] = (s == 0) ? sq : (r[j] + sq);
          }
        }
#pragma unroll
        for (int j = 0; j < 8; ++j) dot = __builtin_fmaf(ev[j], xv[j], dot);
      }
      float xx = ((r[0] + r[1]) + (r[2] + r[3])) + ((r[4] + r[5]) + (r[6] + r[7]));
      float d = (xx - 2.0f * dot) + s_norm[k];
      unsigned long long key =
          ((unsigned long long)__float_as_uint(d) << 10) | (unsigned long long)k;
      atomicMin(&s_key[wv][m], key);
    }
  }

  // safety net (never expected): candidate overflow -> exact full scan
  if (cnt > CMAX) {
    asm volatile("s_waitcnt lgkmcnt(0)" ::: "memory");
    if (l < TPW) {
      const int m = l;
      float xv[DIMV];
      const float4* xr4 = (const float4*)(xin + (size_t)(tb + m) * DIMV);
#pragma unroll
      for (int i = 0; i < 16; ++i) {
        float4 t4 = xr4[i];
        xv[4 * i + 0] = t4.x; xv[4 * i + 1] = t4.y;
        xv[4 * i + 2] = t4.z; xv[4 * i + 3] = t4.w;
      }
      float xx = sumsq64_np(xv);
      float bd = INFINITY; int bk = 0;
      for (int k = 0; k < KC; ++k) {
        const float* e = cb + (size_t)k * DIMV;
        float dot = 0.0f;
#pragma unroll
        for (int i = 0; i < DIMV; ++i) dot = __builtin_fmaf(e[i], xv[i], dot);
        float d = (xx - 2.0f * dot) + s_norm[k];
        if (d < bd) { bd = d; bk = k; }
      }
      s_key[wv][m] =
          ((unsigned long long)__float_as_uint(bd) << 10) | (unsigned long long)bk;
    }
  }
  asm volatile("s_waitcnt lgkmcnt(0)" ::: "memory");

  // ---------------- epilogue: idx, quantized_st, mse, hist (r4 verified) --
  {
    const int m = l & 31, h = l >> 5;
    const int token = tb + m;
    unsigned long long key = s_key[wv][m];
    const int bk = (int)(key & 1023ull);
    if (h == 0) {
      out[OUT_IDX + token] = (float)bk;
      atomicAdd(&s_hist[bk], 1u);
    }
    const float4* q4 = (const float4*)(cb + (size_t)bk * DIMV + h * 32);
    const float4* x4 = (const float4*)(xin + (size_t)token * DIMV + h * 32);
    float* oq = out + OUT_Q + (size_t)token * DIMV + h * 32;
    float mse_part = 0.0f;
#pragma unroll
    for (int rr = 0; rr < 8; ++rr) {
      float4 qv = q4[rr], xv = x4[rr];
      float d0 = qv.x - xv.x, d1 = qv.y - xv.y;
      float d2 = qv.z - xv.z, d3 = qv.w - xv.w;
      float4 o;
      o.x = xv.x + d0; o.y = xv.y + d1; o.z = xv.z + d2; o.w = xv.w + d3;
      mse_part = __builtin_fmaf(d0, d0, mse_part);
      mse_part = __builtin_fmaf(d1, d1, mse_part);
      mse_part = __builtin_fmaf(d2, d2, mse_part);
      mse_part = __builtin_fmaf(d3, d3, mse_part);
      *(float4*)(oq + 4 * rr) = o;
    }
#pragma unroll
    for (int mask = 1; mask < 64; mask <<= 1)
      mse_part += __shfl_xor(mse_part, mask, 64);
    if (l == 0) atomicAdd(ws_mse, mse_part);
  }

  __syncthreads();
  {
    unsigned int c = s_hist[tid];
    if (c) atomicAdd(&ws_hist[tid], c);
  }

  // ---------------- last-block final: perplexity + loss (r5/r6 verified) --
  if (tid == 0) {
    __threadfence();
    unsigned int tkt = atomicAdd(ws_done, 1u);
    s_last = (tkt == (unsigned int)(gridDim.x - 1)) ? 1 : 0;
  }
  __syncthreads();
  if (s_last) {
    __threadfence();
    unsigned int c = atomicAdd(&ws_hist[tid], 0u);   // coherent read
    float p = (float)c / 131072.0f;                  // exact (2^17)
    s_norm[tid] = p * logf(p + 1e-10f);              // p==0 -> 0
    __syncthreads();
#pragma unroll
    for (int s = 512; s > 0; s >>= 1) {
      if (tid < s) s_norm[tid] += s_norm[tid + s];
      __syncthreads();
    }
    if (tid == 0) {
      out[OUT_PERP] = expf(-s_norm[0]);
      float mse = atomicAdd(ws_mse, 0.0f) / 8388608.0f;   // exact (2^23)
      out[OUT_LOSS] = mse + 0.25f * mse;
    }
  }
}

extern "C" void kernel_launch(void* const* d_in, const int* in_sizes, int n_in,
                              void* d_out, int out_size, void* d_ws, size_t ws_size,
                              hipStream_t stream) {
  (void)in_sizes; (void)n_in; (void)out_size; (void)ws_size;
  const float* xin = (const float*)d_in[0];
  const float* cb  = (const float*)d_in[1];
  float* out = (float*)d_out;
  float* ws  = (float*)d_ws;

  hipLaunchKernelGGL(vq_pack_kernel, dim3(32), dim3(256), 0, stream, cb, ws);
  hipLaunchKernelGGL(vq_main_mfma, dim3(NTOK / TPB), dim3(1024), 0, stream,
                     xin, cb, out, ws);
}